// Round 4
// baseline (402.168 us; speedup 1.0000x reference)
//
#include <hip/hip_runtime.h>

// YOLOv1 loss, pred/labels (B,30,7,7) fp32 -> scalar.
// R2-R4: direct scalar loads, 140us. R6: LDS big-group, 132us. R7: LDS
//   double-buffered + counted vmcnt(6), 134us. All three = ~2.9 TB/s
//   app-level read rate; VALU 15%, occ 26%, queues saturated -> throughput
//   wall, structure-independent so far.
// R8: algebraic split + ablation-by-design.
//   Kernel A (cls): ch10-29 masked SSQ is pure elementwise -> full-array
//     float4 grid-stride sweep (16B-aligned m13-replica), obj mask via tiny
//     L2-hot scalar lookup. 67% of bytes at (hopefully) stream rate; also
//     warms L3 with the ch0-9 region.
//   Kernel B (cells): ch0-9 box/iou/conf/noobj per-cell gather, scalar
//     loads, reads L3-warm data.
//   Separate dispatches => separate rocprof rows: if A also runs ~2.9 TB/s,
//   the ceiling is external -> roofline claim next round.

#define GRID 7
#define NCH 30
#define CPI 49                   // cells per image
#define FPI 1470                 // floats per image per tensor
#define CH_CLS0 490              // first element of channel 10 (10*49)
#define OBJ_OFF 196              // channel-4 row offset (4*49)
#define NBLK_A 2048
#define NBLK_B 2048
#define BLK 256

__device__ __forceinline__ float iou_xyxy(float x1a, float y1a, float x2a, float y2a,
                                          float x1b, float y1b, float x2b, float y2b) {
    float iw = fmaxf(fminf(x2a, x2b) - fmaxf(x1a, x1b), 0.0f);
    float ih = fmaxf(fminf(y2a, y2b) - fmaxf(y1a, y1b), 0.0f);
    float inter = iw * ih;
    float a1 = (x2a - x1a) * (y2a - y1a);
    float a2 = (x2b - x1b) * (y2b - y1b);
    float uni = a1 + a2 - inter;
    return inter > 0.0f ? inter / uni : 0.0f;
}

__device__ __forceinline__ void block_reduce_write(float acc, float* dst) {
    #pragma unroll
    for (int off = 32; off > 0; off >>= 1)
        acc += __shfl_down(acc, off, 64);
    __shared__ float rsm[4];
    int lane = threadIdx.x & 63;
    int wid = threadIdx.x >> 6;
    if (lane == 0) rsm[wid] = acc;
    __syncthreads();
    if (threadIdx.x == 0)
        dst[blockIdx.x] = rsm[0] + rsm[1] + rsm[2] + rsm[3];
}

// ---- Kernel A: full-array float4 stream; accumulate obj-masked cls ----
__global__ void __launch_bounds__(BLK) yolo_cls_kernel(
        const float* __restrict__ pred,
        const float* __restrict__ labels,
        float* __restrict__ partials,
        int nElem, float invB) {
    float acc = 0.0f;
    int nf4 = nElem >> 2;
    int stride = gridDim.x * blockDim.x;
    const float4* p4 = reinterpret_cast<const float4*>(pred);
    const float4* l4 = reinterpret_cast<const float4*>(labels);

    for (int i = blockIdx.x * blockDim.x + threadIdx.x; i < nf4; i += stride) {
        float4 pv = p4[i];
        float4 lv = l4[i];
        int e0 = i << 2;
        float pe[4] = {pv.x, pv.y, pv.z, pv.w};
        float le[4] = {lv.x, lv.y, lv.z, lv.w};
        #pragma unroll
        for (int k = 0; k < 4; ++k) {
            int e = e0 + k;
            int img = e / FPI;                 // magic-mul div
            int r = e - img * FPI;
            if (r >= CH_CLS0) {                // channels 10..29 only
                int cell = r % CPI;
                float o = labels[img * FPI + OBJ_OFF + cell];  // L2-hot row
                float d = pe[k] - le[k];
                acc += (o == 1.0f) ? d * d : 0.0f;
            }
        }
    }
    // tail (nElem % 4) — zero for B=32768, guard anyway
    if (blockIdx.x == 0 && threadIdx.x < (nElem & 3)) {
        int e = (nf4 << 2) + threadIdx.x;
        int img = e / FPI;
        int r = e - img * FPI;
        if (r >= CH_CLS0) {
            int cell = r % CPI;
            float o = labels[img * FPI + OBJ_OFF + cell];
            float d = pred[e] - labels[e];
            if (o == 1.0f) acc += d * d;
        }
    }
    block_reduce_write(acc * invB, partials);
}

// ---- Kernel B: per-cell ch0-9 gather (box/iou/conf/noobj, no cls) ----
__global__ void __launch_bounds__(BLK) yolo_cell_kernel(
        const float* __restrict__ pred,
        const float* __restrict__ labels,
        float* __restrict__ partials,
        int ncells, float invB) {
    float acc = 0.0f;
    int stride = gridDim.x * blockDim.x;
    for (int t = blockIdx.x * blockDim.x + threadIdx.x; t < ncells; t += stride) {
        int img = t / CPI;
        int cell = t - img * CPI;
        int m = cell / GRID;                   // dim-2 index, pairs with x
        int n = cell - m * GRID;               // dim-3 index, pairs with y

        const float* pb = pred + img * FPI + cell;
        const float* lb = labels + img * FPI + cell;

        float p0 = pb[0 * CPI], p1 = pb[1 * CPI], p2 = pb[2 * CPI], p3 = pb[3 * CPI];
        float p4 = pb[4 * CPI], p5 = pb[5 * CPI], p6 = pb[6 * CPI], p7 = pb[7 * CPI];
        float p8 = pb[8 * CPI], p9 = pb[9 * CPI];
        float l0 = lb[0 * CPI], l1 = lb[1 * CPI], l2 = lb[2 * CPI], l3 = lb[3 * CPI];
        float lobj = lb[4 * CPI];
        float l5 = lb[5 * CPI], l6 = lb[6 * CPI], l7 = lb[7 * CPI], l8 = lb[8 * CPI];

        const float inv_g = 1.0f / (float)GRID;
        float fm = (float)m, fn = (float)n;

        float cx = (p0 + fm) * inv_g, cy = (p1 + fn) * inv_g;
        float b1x1 = cx - p2 * 0.5f, b1y1 = cy - p3 * 0.5f;
        float b1x2 = cx + p2 * 0.5f, b1y2 = cy + p3 * 0.5f;
        cx = (p5 + fm) * inv_g; cy = (p6 + fn) * inv_g;
        float b2x1 = cx - p7 * 0.5f, b2y1 = cy - p8 * 0.5f;
        float b2x2 = cx + p7 * 0.5f, b2y2 = cy + p8 * 0.5f;
        cx = (l0 + fm) * inv_g; cy = (l1 + fn) * inv_g;
        float gx1 = cx - l2 * 0.5f, gy1 = cy - l3 * 0.5f;
        float gx2 = cx + l2 * 0.5f, gy2 = cy + l3 * 0.5f;

        float iou1 = iou_xyxy(b1x1, b1y1, b1x2, b1y2, gx1, gy1, gx2, gy2);
        float iou2 = iou_xyxy(b2x1, b2y1, b2x2, b2y2, gx1, gy1, gx2, gy2);
        bool resp1 = iou1 >= iou2;

        float dx = p0 - l0, dy = p1 - l1;
        float dw = sqrtf(p2) - sqrtf(l2), dh = sqrtf(p3) - sqrtf(l3);
        float coor1 = 5.0f * (dx * dx + dy * dy + dw * dw + dh * dh);
        dx = p5 - l5; dy = p6 - l6;
        dw = sqrtf(p7) - sqrtf(l7); dh = sqrtf(p8) - sqrtf(l8);
        float coor2 = 5.0f * (dx * dx + dy * dy + dw * dw + dh * dh);

        float e1 = p4 - iou1, e2 = p9 - iou2;
        float loss_b1 = coor1 + e1 * e1 + 0.5f * e2 * e2;
        float loss_b2 = coor2 + e2 * e2 + 0.5f * e1 * e1;

        float obj_loss = resp1 ? loss_b1 : loss_b2;      // cls added in kernel A
        float noobj_loss = 0.5f * (p4 * p4 + p9 * p9);

        acc += (lobj == 1.0f) ? obj_loss : noobj_loss;
    }
    block_reduce_write(acc * invB, partials);
}

__global__ void __launch_bounds__(256) yolo_final_kernel(
        const float* __restrict__ partials, float* __restrict__ out, int np) {
    float acc = 0.0f;
    for (int i = threadIdx.x; i < np; i += 256)
        acc += partials[i];
    #pragma unroll
    for (int off = 32; off > 0; off >>= 1)
        acc += __shfl_down(acc, off, 64);
    __shared__ float rsm[4];
    int lane = threadIdx.x & 63;
    int wid = threadIdx.x >> 6;
    if (lane == 0) rsm[wid] = acc;
    __syncthreads();
    if (threadIdx.x == 0)
        out[0] = rsm[0] + rsm[1] + rsm[2] + rsm[3];
}

extern "C" void kernel_launch(void* const* d_in, const int* in_sizes, int n_in,
                              void* d_out, int out_size, void* d_ws, size_t ws_size,
                              hipStream_t stream) {
    const float* pred = (const float*)d_in[0];
    const float* labels = (const float*)d_in[1];
    float* out = (float*)d_out;
    float* partials = (float*)d_ws;

    int total = in_sizes[0];           // element count per tensor
    int B = total / FPI;               // 32768
    if (B <= 0) return;
    float invB = 1.0f / (float)B;
    int ncells = B * CPI;              // 1,605,632

    // partials: [0, na) for kernel A, [na, na+nb) for kernel B
    int na = NBLK_A, nb = NBLK_B;
    size_t cap = ws_size / sizeof(float);
    if ((size_t)(na + nb) > cap) {     // defensive: shrink into workspace
        na = (int)(cap / 2) > 0 ? (int)(cap / 2) : 1;
        nb = na;
    }

    yolo_cls_kernel<<<na, BLK, 0, stream>>>(pred, labels, partials, total, invB);
    yolo_cell_kernel<<<nb, BLK, 0, stream>>>(pred, labels, partials + na,
                                             ncells, invB);
    yolo_final_kernel<<<1, 256, 0, stream>>>(partials, out, na + nb);
}

// Round 5
// 382.586 us; speedup vs baseline: 1.0512x; 1.0512x over previous
//
#include <hip/hip_runtime.h>

// YOLOv1 loss, pred/labels (B,30,7,7) fp32 -> scalar.
// R2-R8 finding: four structures (scalar gather 140us, LDS-drain 132, LDS
//   double-buffered+vmcnt(6) 134, pure float4 stream 124) all = 2.9-3.1 TB/s
//   app-level read rate. R8 replay rows: fully L3-resident data (FETCH~0)
//   runs the SAME 124us -> the wall is the CU-side vector-load return path
//   (~5 B/cyc/CU = 3.1 TB/s chip; m13 copy's read half = same number).
// R9: read FEWER bytes. noobj cells (70%) need only pred4, pred9, lab4
//   (3/60 floats). Per-lane predicated loads for the other 57 (obj cells,
//   30%): exec-masked lanes issue no TA requests. Expected register-traffic
//   386MB -> 129MB (3x). If neutral, the limit is L1 line-fill granular ->
//   roofline established (every line contains >=1 obj cell at p=0.3).

#define GRID 7
#define NCH 30
#define CPI 49                   // cells per image
#define FPI 1470                 // floats per image per tensor
#define NBLK 2048
#define BLK 256

__device__ __forceinline__ float iou_xyxy(float x1a, float y1a, float x2a, float y2a,
                                          float x1b, float y1b, float x2b, float y2b) {
    float iw = fmaxf(fminf(x2a, x2b) - fmaxf(x1a, x1b), 0.0f);
    float ih = fmaxf(fminf(y2a, y2b) - fmaxf(y1a, y1b), 0.0f);
    float inter = iw * ih;
    float a1 = (x2a - x1a) * (y2a - y1a);
    float a2 = (x2b - x1b) * (y2b - y1b);
    float uni = a1 + a2 - inter;
    return inter > 0.0f ? inter / uni : 0.0f;
}

__device__ __forceinline__ void block_reduce_write(float acc, float* dst) {
    #pragma unroll
    for (int off = 32; off > 0; off >>= 1)
        acc += __shfl_down(acc, off, 64);
    __shared__ float rsm[4];
    int lane = threadIdx.x & 63;
    int wid = threadIdx.x >> 6;
    if (lane == 0) rsm[wid] = acc;
    __syncthreads();
    if (threadIdx.x == 0)
        dst[blockIdx.x] = rsm[0] + rsm[1] + rsm[2] + rsm[3];
}

__global__ void __launch_bounds__(BLK) yolo_partial_kernel(
        const float* __restrict__ pred,
        const float* __restrict__ labels,
        float* __restrict__ partials,
        int ncells, float invB) {
    float acc = 0.0f;
    int stride = gridDim.x * blockDim.x;

    for (int t = blockIdx.x * blockDim.x + threadIdx.x; t < ncells; t += stride) {
        int img = t / CPI;
        int cell = t - img * CPI;

        const float* pb = pred   + img * FPI + cell;
        const float* lb = labels + img * FPI + cell;

        // Always needed (3/60 floats): obj mask + the two confidences.
        float lobj = lb[4 * CPI];
        float p4 = pb[4 * CPI];
        float p9 = pb[9 * CPI];

        if (lobj == 1.0f) {
            // Obj cell (~30% of lanes): gather the remaining 57 floats.
            // Exec-masked-out lanes issue no requests for these loads.
            int m = cell / GRID;               // dim-2 index, pairs with x
            int n = cell - m * GRID;           // dim-3 index, pairs with y
            float fm = (float)m, fn = (float)n;

            float p0 = pb[0 * CPI], p1 = pb[1 * CPI], p2 = pb[2 * CPI], p3 = pb[3 * CPI];
            float p5 = pb[5 * CPI], p6 = pb[6 * CPI], p7 = pb[7 * CPI], p8 = pb[8 * CPI];
            float l0 = lb[0 * CPI], l1 = lb[1 * CPI], l2 = lb[2 * CPI], l3 = lb[3 * CPI];
            float l5 = lb[5 * CPI], l6 = lb[6 * CPI], l7 = lb[7 * CPI], l8 = lb[8 * CPI];

            float cls = 0.0f;
            #pragma unroll
            for (int c = 10; c < NCH; ++c) {
                float d = pb[c * CPI] - lb[c * CPI];
                cls += d * d;
            }

            const float inv_g = 1.0f / (float)GRID;

            float cx = (p0 + fm) * inv_g, cy = (p1 + fn) * inv_g;
            float b1x1 = cx - p2 * 0.5f, b1y1 = cy - p3 * 0.5f;
            float b1x2 = cx + p2 * 0.5f, b1y2 = cy + p3 * 0.5f;
            cx = (p5 + fm) * inv_g; cy = (p6 + fn) * inv_g;
            float b2x1 = cx - p7 * 0.5f, b2y1 = cy - p8 * 0.5f;
            float b2x2 = cx + p7 * 0.5f, b2y2 = cy + p8 * 0.5f;
            cx = (l0 + fm) * inv_g; cy = (l1 + fn) * inv_g;
            float gx1 = cx - l2 * 0.5f, gy1 = cy - l3 * 0.5f;
            float gx2 = cx + l2 * 0.5f, gy2 = cy + l3 * 0.5f;

            float iou1 = iou_xyxy(b1x1, b1y1, b1x2, b1y2, gx1, gy1, gx2, gy2);
            float iou2 = iou_xyxy(b2x1, b2y1, b2x2, b2y2, gx1, gy1, gx2, gy2);
            bool resp1 = iou1 >= iou2;

            float dx = p0 - l0, dy = p1 - l1;
            float dw = sqrtf(p2) - sqrtf(l2), dh = sqrtf(p3) - sqrtf(l3);
            float coor1 = 5.0f * (dx * dx + dy * dy + dw * dw + dh * dh);
            dx = p5 - l5; dy = p6 - l6;
            dw = sqrtf(p7) - sqrtf(l7); dh = sqrtf(p8) - sqrtf(l8);
            float coor2 = 5.0f * (dx * dx + dy * dy + dw * dw + dh * dh);

            float e1 = p4 - iou1, e2 = p9 - iou2;
            float loss_b1 = coor1 + e1 * e1 + 0.5f * e2 * e2;
            float loss_b2 = coor2 + e2 * e2 + 0.5f * e1 * e1;

            acc += (resp1 ? loss_b1 : loss_b2) + cls;
        } else {
            acc += 0.5f * (p4 * p4 + p9 * p9);
        }
    }
    block_reduce_write(acc * invB, partials);
}

__global__ void __launch_bounds__(256) yolo_final_kernel(
        const float* __restrict__ partials, float* __restrict__ out, int np) {
    float acc = 0.0f;
    for (int i = threadIdx.x; i < np; i += 256)
        acc += partials[i];
    #pragma unroll
    for (int off = 32; off > 0; off >>= 1)
        acc += __shfl_down(acc, off, 64);
    __shared__ float rsm[4];
    int lane = threadIdx.x & 63;
    int wid = threadIdx.x >> 6;
    if (lane == 0) rsm[wid] = acc;
    __syncthreads();
    if (threadIdx.x == 0)
        out[0] = rsm[0] + rsm[1] + rsm[2] + rsm[3];
}

extern "C" void kernel_launch(void* const* d_in, const int* in_sizes, int n_in,
                              void* d_out, int out_size, void* d_ws, size_t ws_size,
                              hipStream_t stream) {
    const float* pred = (const float*)d_in[0];
    const float* labels = (const float*)d_in[1];
    float* out = (float*)d_out;
    float* partials = (float*)d_ws;

    int total = in_sizes[0];           // element count per tensor
    int B = total / FPI;               // 32768
    if (B <= 0) return;
    float invB = 1.0f / (float)B;
    int ncells = B * CPI;              // 1,605,632

    int nblk = NBLK;
    size_t cap = ws_size / sizeof(float);
    if ((size_t)nblk > cap) nblk = (int)cap > 0 ? (int)cap : 1;

    yolo_partial_kernel<<<nblk, BLK, 0, stream>>>(pred, labels, partials,
                                                  ncells, invB);
    yolo_final_kernel<<<1, 256, 0, stream>>>(partials, out, nblk);
}